// Round 3
// baseline (801.481 us; speedup 1.0000x reference)
//
#include <hip/hip_runtime.h>

// GCN pipeline on MI355X, round 4:
//   deg/dinv -> CSR(by dst) -> GEMM1(all-register, barrier-free) -> agg+relu(4-deep)
//   -> GEMM2(same template) -> agg+relu -> BN stats -> fused BN+LN -> out
// GEMM redesign (no LDS, no barriers): B (<=512KB) is L2-resident and shared by all
// blocks, so B fragments are loaded per-lane directly from global (L2 hits),
// double-buffered in registers one iter ahead. A loaded per-lane direct from HBM,
// 2 iters ahead. Wave = 32 rows x 128 cols (acc 2x8), block = 64x256 -> A read once.
// All array indices compile-time (macros with literal parity) to avoid scratch.

typedef __attribute__((ext_vector_type(4))) float f32x4;
typedef __attribute__((ext_vector_type(8))) _Float16 f16x8;
typedef __attribute__((ext_vector_type(4))) _Float16 f16x4;

#define NN 50000
#define NF 1024
#define NH 256

// ---------------- small kernels: degree / dinv -------------------------------
__global__ __launch_bounds__(256) void deg_count(const int* __restrict__ ei,
    const float* __restrict__ ew, float* __restrict__ deg, int* __restrict__ cnt, int E)
{
    int e = blockIdx.x * 256 + threadIdx.x;
    if (e >= E) return;
    int d = ei[E + e];
    atomicAdd(&deg[d], ew[e]);
    atomicAdd(&cnt[d], 1);
}

__global__ __launch_bounds__(256) void dinv_k(const float* __restrict__ deg,
    float* __restrict__ dinv, int n)
{
    int i = blockIdx.x * 256 + threadIdx.x;
    if (i < n) dinv[i] = rsqrtf(deg[i] + 1.0f);   // +1 = self-loop weight
}

// ---------------- CSR build: 3-kernel exclusive scan + scatter ---------------
__global__ __launch_bounds__(512) void scan_a(const int* __restrict__ cnt,
    int* __restrict__ excl, int* __restrict__ bsum, int n)
{
    __shared__ int sm[512];
    int t = threadIdx.x, g = blockIdx.x * 512 + t;
    int v = (g < n) ? cnt[g] : 0;
    sm[t] = v;
    __syncthreads();
    for (int d = 1; d < 512; d <<= 1) {
        int x = (t >= d) ? sm[t - d] : 0;
        __syncthreads();
        sm[t] += x;
        __syncthreads();
    }
    if (g < n) excl[g] = sm[t] - v;
    if (t == 511) bsum[blockIdx.x] = sm[511];
}

__global__ __launch_bounds__(128) void scan_b(int* __restrict__ bsum, int nb)
{
    __shared__ int sm[128];
    int t = threadIdx.x;
    int v = (t < nb) ? bsum[t] : 0;
    sm[t] = v;
    __syncthreads();
    for (int d = 1; d < 128; d <<= 1) {
        int x = (t >= d) ? sm[t - d] : 0;
        __syncthreads();
        sm[t] += x;
        __syncthreads();
    }
    if (t < nb) bsum[t] = sm[t] - v;
}

__global__ __launch_bounds__(256) void scan_c(const int* __restrict__ excl,
    const int* __restrict__ bsum, int* __restrict__ offs, int n, int E)
{
    int g = blockIdx.x * 256 + threadIdx.x;
    if (g < n) offs[g] = excl[g] + bsum[g >> 9];
    else if (g == n) offs[n] = E;
}

__global__ __launch_bounds__(256) void scatter_k(const int* __restrict__ ei,
    const float* __restrict__ ew, const int* __restrict__ offs,
    int* __restrict__ cursor, const float* __restrict__ dinv,
    int* __restrict__ csrc, float* __restrict__ cwv, int E)
{
    int e = blockIdx.x * 256 + threadIdx.x;
    if (e >= E) return;
    int s = ei[e], d = ei[E + e];
    int pos = offs[d] + atomicAdd(&cursor[d], 1);
    csrc[pos] = s;
    cwv[pos] = ew[e] * dinv[s] * dinv[d];
}

// ---------------- W -> W^T f16 conversion ------------------------------------
__global__ __launch_bounds__(256) void cvt_w(const float* __restrict__ W,
    unsigned short* __restrict__ WT, int K, int total)
{
    int idx = blockIdx.x * 256 + threadIdx.x;
    if (idx >= total) return;
    int k = idx >> 8, n = idx & 255;
    ((_Float16*)WT)[(size_t)n * K + k] = (_Float16)W[idx];
}

// ---------------- GEMM: C[M][256](f16) = A[M][K] * B^T, f16 MFMA -------------
// Block: 64 rows x 256 cols, 4 waves in 2x2: wave (wr,wc) owns rows
// [m0+wr*32, +32) x cols [wc*128, +128). Per K-step (32): af[2] x bf[8] -> 16 MFMA.
// No LDS, no barriers. B regs double-buffered (1 iter lead, L2-hit);
// A regs 2 slots (2 iter lead, HBM stream).
#define ISSUE_B(kt, p)                                                          \
    {                                                                           \
        _Pragma("unroll")                                                       \
        for (int j = 0; j < 8; ++j)                                             \
            bpre[p][j] = *(const f16x8*)(Bbase + (size_t)j * 16 * K + ((kt) << 5)); \
    }

#define ISSUE_A(kt, p)                                                          \
    {                                                                           \
        if constexpr (AF32) {                                                   \
            const float* g0 = Af + (size_t)row0 * K + ((kt) << 5) + q * 8;      \
            const float* g1 = Af + (size_t)row1 * K + ((kt) << 5) + q * 8;      \
            apre[p][0] = *(const f32x4*)g0;                                     \
            apre[p][1] = *(const f32x4*)(g0 + 4);                               \
            apre[p][2] = *(const f32x4*)g1;                                     \
            apre[p][3] = *(const f32x4*)(g1 + 4);                               \
        } else {                                                                \
            aph[p][0] = *(const f16x8*)(Ah + (size_t)row0 * K + ((kt) << 5) + q * 8); \
            aph[p][1] = *(const f16x8*)(Ah + (size_t)row1 * K + ((kt) << 5) + q * 8); \
        }                                                                       \
    }

#define BODY(k, p, pn)                                                          \
    {                                                                           \
        if ((k) + 1 < T) ISSUE_B((k) + 1, pn);                                  \
        f16x8 af0, af1;                                                         \
        if constexpr (AF32) {                                                   \
            _Pragma("unroll")                                                   \
            for (int e = 0; e < 4; ++e) {                                       \
                af0[e]     = (_Float16)apre[p][0][e];                           \
                af0[4 + e] = (_Float16)apre[p][1][e];                           \
                af1[e]     = (_Float16)apre[p][2][e];                           \
                af1[4 + e] = (_Float16)apre[p][3][e];                           \
            }                                                                   \
        } else {                                                                \
            af0 = aph[p][0];                                                    \
            af1 = aph[p][1];                                                    \
        }                                                                       \
        if ((k) + 2 < T) ISSUE_A((k) + 2, p);                                   \
        _Pragma("unroll")                                                       \
        for (int j = 0; j < 8; ++j) {                                           \
            acc[0][j] = __builtin_amdgcn_mfma_f32_16x16x32_f16(af0, bpre[p][j], acc[0][j], 0, 0, 0); \
            acc[1][j] = __builtin_amdgcn_mfma_f32_16x16x32_f16(af1, bpre[p][j], acc[1][j], 0, 0, 0); \
        }                                                                       \
    }

template<bool AF32>
__global__ __launch_bounds__(256, 2) void gemm_reg(
    const void* __restrict__ Av, const unsigned short* __restrict__ BT,
    _Float16* __restrict__ C, int M, int K)
{
    const int t = threadIdx.x;
    const int lane = t & 63, wid = t >> 6;
    const int r = lane & 15, q = lane >> 4;
    const int wr = wid >> 1, wc = wid & 1;
    const int m0 = blockIdx.x * 64;
    const float* Af = (const float*)Av;
    const _Float16* Ah = (const _Float16*)Av;

    int row0 = m0 + wr * 32 + r;
    int row1 = row0 + 16;
    if (row0 >= M) row0 = M - 1;    // dup row; store is guarded
    if (row1 >= M) row1 = M - 1;

    // lane's B base: col n = wc*128 + (j*16) + r, k-offset q*8
    const _Float16* Bbase = (const _Float16*)BT + (size_t)(wc * 128 + r) * K + q * 8;

    f32x4 acc[2][8];
#pragma unroll
    for (int i = 0; i < 2; ++i)
#pragma unroll
        for (int j = 0; j < 8; ++j) acc[i][j] = (f32x4){0.f, 0.f, 0.f, 0.f};

    f32x4 apre[2][4];
    f16x8 aph[2][2];
    f16x8 bpre[2][8];

    const int T = K >> 5;   // 32 (K=1024) or 8 (K=256); always even

    ISSUE_B(0, 0);
    ISSUE_A(0, 0);
    ISSUE_A(1, 1);

    for (int k = 0; k < T; k += 2) {
        BODY(k, 0, 1);
        BODY(k + 1, 1, 0);
    }

    // epilogue: D[row = q*4+reg][col = j*16+r] per 16x16 tile
#pragma unroll
    for (int i = 0; i < 2; ++i) {
#pragma unroll
        for (int reg = 0; reg < 4; ++reg) {
            int m = m0 + wr * 32 + i * 16 + q * 4 + reg;
            if (m < M) {
                _Float16* cp = C + (size_t)m * 256 + wc * 128 + r;
#pragma unroll
                for (int j = 0; j < 8; ++j) cp[j * 16] = (_Float16)acc[i][j][reg];
            }
        }
    }
}

// ---------------- aggregation: out = relu(A_hat @ h + b), f16 in/out ---------
// 1 wave per node; lane holds cols [4*lane, 4*lane+4). Edge metadata loaded
// cooperatively (64 edges/coalesced load), broadcast via shfl; 4 independent
// gathers in flight per step to hide L2/L3 latency.
__global__ __launch_bounds__(256) void agg_relu(
    const _Float16* __restrict__ h, const int* __restrict__ roff,
    const int* __restrict__ csrc, const float* __restrict__ cwv,
    const float* __restrict__ dinv, const float* __restrict__ bias,
    _Float16* __restrict__ out, int n)
{
    const int lane = threadIdx.x & 63, wid = threadIdx.x >> 6;
    const int i = blockIdx.x * 4 + wid;
    if (i >= n) return;
    const int c = lane << 2;
    const float di = dinv[i];
    const float sw = di * di;
    const f16x4 hv = *(const f16x4*)(h + (size_t)i * 256 + c);
    float a0 = sw * (float)hv.x, a1 = sw * (float)hv.y;
    float a2 = sw * (float)hv.z, a3 = sw * (float)hv.w;
    float b0 = 0.f, b1 = 0.f, b2 = 0.f, b3 = 0.f;
    float c0 = 0.f, c1 = 0.f, c2 = 0.f, c3 = 0.f;
    float d0 = 0.f, d1 = 0.f, d2 = 0.f, d3 = 0.f;
    const int p0 = roff[i], pe = roff[i + 1];
    for (int base = p0; base < pe; base += 64) {
        int lim = pe - base; if (lim > 64) lim = 64;
        int sv = 0; float wv = 0.f;
        if (lane < lim) { sv = csrc[base + lane]; wv = cwv[base + lane]; }
        int j = 0;
        for (; j + 3 < lim; j += 4) {
            int s0 = __shfl(sv, j),     s1 = __shfl(sv, j + 1);
            int s2 = __shfl(sv, j + 2), s3 = __shfl(sv, j + 3);
            float w0 = __shfl(wv, j),     w1 = __shfl(wv, j + 1);
            float w2 = __shfl(wv, j + 2), w3 = __shfl(wv, j + 3);
            f16x4 v0 = *(const f16x4*)(h + (size_t)s0 * 256 + c);
            f16x4 v1 = *(const f16x4*)(h + (size_t)s1 * 256 + c);
            f16x4 v2 = *(const f16x4*)(h + (size_t)s2 * 256 + c);
            f16x4 v3 = *(const f16x4*)(h + (size_t)s3 * 256 + c);
            a0 += w0 * (float)v0.x; a1 += w0 * (float)v0.y;
            a2 += w0 * (float)v0.z; a3 += w0 * (float)v0.w;
            b0 += w1 * (float)v1.x; b1 += w1 * (float)v1.y;
            b2 += w1 * (float)v1.z; b3 += w1 * (float)v1.w;
            c0 += w2 * (float)v2.x; c1 += w2 * (float)v2.y;
            c2 += w2 * (float)v2.z; c3 += w2 * (float)v2.w;
            d0 += w3 * (float)v3.x; d1 += w3 * (float)v3.y;
            d2 += w3 * (float)v3.z; d3 += w3 * (float)v3.w;
        }
        for (; j < lim; ++j) {
            int s0 = __shfl(sv, j);
            float w0 = __shfl(wv, j);
            f16x4 v0 = *(const f16x4*)(h + (size_t)s0 * 256 + c);
            a0 += w0 * (float)v0.x; a1 += w0 * (float)v0.y;
            a2 += w0 * (float)v0.z; a3 += w0 * (float)v0.w;
        }
    }
    const float4 bb = *(const float4*)(bias + c);
    f16x4 o;
    o.x = (_Float16)fmaxf(a0 + b0 + c0 + d0 + bb.x, 0.f);
    o.y = (_Float16)fmaxf(a1 + b1 + c1 + d1 + bb.y, 0.f);
    o.z = (_Float16)fmaxf(a2 + b2 + c2 + d2 + bb.z, 0.f);
    o.w = (_Float16)fmaxf(a3 + b3 + c3 + d3 + bb.w, 0.f);
    *(f16x4*)(out + (size_t)i * 256 + c) = o;
}

// ---------------- BatchNorm stats (per-column over rows), f16 in -------------
__global__ __launch_bounds__(256) void bn_stats(const _Float16* __restrict__ h,
    float* __restrict__ bnsum, float* __restrict__ bnsq, int n)
{
    const int t = threadIdx.x;
    float s = 0.f, s2 = 0.f;
    for (int r = blockIdx.x; r < n; r += gridDim.x) {
        float v = (float)h[(size_t)r * 256 + t];
        s += v; s2 += v * v;
    }
    atomicAdd(&bnsum[t], s);
    atomicAdd(&bnsq[t], s2);
}

__global__ __launch_bounds__(256) void bn_params(const float* __restrict__ bnsum,
    const float* __restrict__ bnsq, const float* __restrict__ gamma,
    const float* __restrict__ beta, float* __restrict__ scale,
    float* __restrict__ shift, int n)
{
    int t = threadIdx.x;
    float mu = bnsum[t] / (float)n;
    float var = bnsq[t] / (float)n - mu * mu;
    float sc = gamma[t] * rsqrtf(var + 1e-5f);
    scale[t] = sc;
    shift[t] = beta[t] - mu * sc;
}

// ---------------- fused BN affine + LayerNorm, f16 in / fp32 out -------------
__global__ __launch_bounds__(256) void bn_ln(const _Float16* __restrict__ h,
    const float* __restrict__ scale, const float* __restrict__ shift,
    const float* __restrict__ lng, const float* __restrict__ lnb,
    float* __restrict__ out, int n)
{
    const int lane = threadIdx.x & 63, wid = threadIdx.x >> 6;
    const int i = blockIdx.x * 4 + wid;
    if (i >= n) return;
    const int c = lane << 2;
    const f16x4 v = *(const f16x4*)(h + (size_t)i * 256 + c);
    const float4 sc = *(const float4*)(scale + c);
    const float4 sh = *(const float4*)(shift + c);
    float y0 = (float)v.x * sc.x + sh.x;
    float y1 = (float)v.y * sc.y + sh.y;
    float y2 = (float)v.z * sc.z + sh.z;
    float y3 = (float)v.w * sc.w + sh.w;
    float ps = y0 + y1 + y2 + y3;
    float ps2 = y0 * y0 + y1 * y1 + y2 * y2 + y3 * y3;
#pragma unroll
    for (int off = 32; off > 0; off >>= 1) {
        ps += __shfl_down(ps, off);
        ps2 += __shfl_down(ps2, off);
    }
    ps = __shfl(ps, 0);
    ps2 = __shfl(ps2, 0);
    const float mu = ps * (1.f / 256.f);
    const float var = ps2 * (1.f / 256.f) - mu * mu;
    const float rs = rsqrtf(var + 1e-5f);
    const float4 g = *(const float4*)(lng + c);
    const float4 bb = *(const float4*)(lnb + c);
    float4 o;
    o.x = (y0 - mu) * rs * g.x + bb.x;
    o.y = (y1 - mu) * rs * g.y + bb.y;
    o.z = (y2 - mu) * rs * g.z + bb.z;
    o.w = (y3 - mu) * rs * g.w + bb.w;
    *(float4*)(out + (size_t)i * 256 + c) = o;
}

// ---------------- launcher ---------------------------------------------------
extern "C" void kernel_launch(void* const* d_in, const int* in_sizes, int n_in,
                              void* d_out, int out_size, void* d_ws, size_t ws_size,
                              hipStream_t stream)
{
    const float* x   = (const float*)d_in[0];
    const int*   ei  = (const int*)d_in[1];
    const float* ew  = (const float*)d_in[2];
    const float* W1  = (const float*)d_in[3];
    const float* b1  = (const float*)d_in[4];
    const float* W2  = (const float*)d_in[5];
    const float* b2  = (const float*)d_in[6];
    const float* bng = (const float*)d_in[7];
    const float* bnb = (const float*)d_in[8];
    const float* lng = (const float*)d_in[9];
    const float* lnb = (const float*)d_in[10];
    float* out = (float*)d_out;

    const int N = NN;
    const int E = in_sizes[2];

    char* ws = (char*)d_ws;
    size_t o = 0;
    auto alloc = [&](size_t b) -> char* {
        char* p = ws + o;
        o = (o + b + 255) & ~(size_t)255;
        return p;
    };
    _Float16* h1  = (_Float16*)alloc((size_t)N * NH * 2);   // GEMM out (reused for h2)
    _Float16* h1a = (_Float16*)alloc((size_t)N * NH * 2);
    _Float16* h2a = (_Float16*)alloc((size_t)N * NH * 2);
    unsigned short* W1T = (unsigned short*)alloc((size_t)NH * NF * 2);
    unsigned short* W2T = (unsigned short*)alloc((size_t)NH * NH * 2);
    int*   csrc = (int*)alloc((size_t)E * 4);
    float* cwv  = (float*)alloc((size_t)E * 4);
    int*   offs = (int*)alloc((size_t)(N + 1) * 4);
    int*   excl = (int*)alloc((size_t)N * 4);
    int*   bsum = (int*)alloc(512);
    float* dinv = (float*)alloc((size_t)N * 4);
    float* bnscale = (float*)alloc(NH * 4);
    float* bnshift = (float*)alloc(NH * 4);
    char* zbase = ws + o;
    float* deg    = (float*)alloc((size_t)N * 4);
    int*   cnt    = (int*)alloc((size_t)N * 4);
    int*   cursor = (int*)alloc((size_t)N * 4);
    float* bnsum  = (float*)alloc(NH * 4);
    float* bnsq   = (float*)alloc(NH * 4);
    size_t zbytes = (size_t)((ws + o) - zbase);
    (void)hipMemsetAsync(zbase, 0, zbytes, stream);

    cvt_w<<<(NF * NH + 255) / 256, 256, 0, stream>>>(W1, W1T, NF, NF * NH);
    cvt_w<<<(NH * NH + 255) / 256, 256, 0, stream>>>(W2, W2T, NH, NH * NH);
    deg_count<<<(E + 255) / 256, 256, 0, stream>>>(ei, ew, deg, cnt, E);
    dinv_k<<<(N + 255) / 256, 256, 0, stream>>>(deg, dinv, N);
    scan_a<<<(N + 511) / 512, 512, 0, stream>>>(cnt, excl, bsum, N);
    scan_b<<<1, 128, 0, stream>>>(bsum, (N + 511) / 512);
    scan_c<<<(N + 1 + 255) / 256, 256, 0, stream>>>(excl, bsum, offs, N, E);
    scatter_k<<<(E + 255) / 256, 256, 0, stream>>>(ei, ew, offs, cursor, dinv, csrc, cwv, E);

    const int gblk = (N + 63) / 64;   // 782
    gemm_reg<true><<<gblk, 256, 0, stream>>>(x, W1T, h1, N, NF);
    agg_relu<<<(N + 3) / 4, 256, 0, stream>>>(h1, offs, csrc, cwv, dinv, b1, h1a, N);
    gemm_reg<false><<<gblk, 256, 0, stream>>>(h1a, W2T, h1, N, NH);
    agg_relu<<<(N + 3) / 4, 256, 0, stream>>>(h1, offs, csrc, cwv, dinv, b2, h2a, N);

    bn_stats<<<256, 256, 0, stream>>>(h2a, bnsum, bnsq, N);
    bn_params<<<1, 256, 0, stream>>>(bnsum, bnsq, bng, bnb, bnscale, bnshift, N);
    bn_ln<<<(N + 3) / 4, 256, 0, stream>>>(h2a, bnscale, bnshift, lng, lnb, out, N);
}

// Round 4
// 645.781 us; speedup vs baseline: 1.2411x; 1.2411x over previous
//
#include <hip/hip_runtime.h>

// GCN pipeline on MI355X, round 5:
//   deg/dinv(packed u64 atomic) -> CSR -> GEMM1(reg-staged dbuf, padded LDS,
//   raw-barrier pipeline) -> agg+relu -> GEMM2(same) -> agg+relu -> BN -> BN+LN
// GEMM: 128x128 tile, 4 waves. A and B staged global->reg (coalesced, compiler-
// tracked counted vmcnt) 2 iters ahead, then reg->LDS (stride 40 f16: all
// read/write patterns <=2-way bank aliasing = free). One raw s_barrier per iter
// with lgkmcnt(0) only -- in-flight prefetch loads survive the barrier.

typedef __attribute__((ext_vector_type(4))) float f32x4;
typedef __attribute__((ext_vector_type(8))) _Float16 f16x8;
typedef __attribute__((ext_vector_type(4))) _Float16 f16x4;

#define NN 50000
#define NF 1024
#define NH 256

// ---------------- degree+count in ONE u64 atomic per edge --------------------
// dc[d] accumulates: (count << 40) | round(w * 2^24). deg < ~64 -> low40 < 2^30.
__global__ __launch_bounds__(256) void deg_count(const int* __restrict__ ei,
    const float* __restrict__ ew, unsigned long long* __restrict__ dc, int E)
{
    int e = blockIdx.x * 256 + threadIdx.x;
    if (e >= E) return;
    int d = ei[E + e];
    unsigned long long pack = (1ull << 40) |
        (unsigned long long)(unsigned int)(ew[e] * 16777216.0f + 0.5f);
    atomicAdd(&dc[d], pack);
}

__global__ __launch_bounds__(256) void dinv_k(const unsigned long long* __restrict__ dc,
    float* __restrict__ dinv, int n)
{
    int i = blockIdx.x * 256 + threadIdx.x;
    if (i < n) {
        float deg = (float)(dc[i] & 0xFFFFFFFFFFull) * (1.0f / 16777216.0f);
        dinv[i] = rsqrtf(deg + 1.0f);   // +1 = self-loop weight
    }
}

// ---------------- CSR build: 3-kernel exclusive scan + scatter ---------------
__global__ __launch_bounds__(512) void scan_a(const unsigned long long* __restrict__ dc,
    int* __restrict__ excl, int* __restrict__ bsum, int n)
{
    __shared__ int sm[512];
    int t = threadIdx.x, g = blockIdx.x * 512 + t;
    int v = (g < n) ? (int)(dc[g] >> 40) : 0;
    sm[t] = v;
    __syncthreads();
    for (int d = 1; d < 512; d <<= 1) {
        int x = (t >= d) ? sm[t - d] : 0;
        __syncthreads();
        sm[t] += x;
        __syncthreads();
    }
    if (g < n) excl[g] = sm[t] - v;
    if (t == 511) bsum[blockIdx.x] = sm[511];
}

__global__ __launch_bounds__(128) void scan_b(int* __restrict__ bsum, int nb)
{
    __shared__ int sm[128];
    int t = threadIdx.x;
    int v = (t < nb) ? bsum[t] : 0;
    sm[t] = v;
    __syncthreads();
    for (int d = 1; d < 128; d <<= 1) {
        int x = (t >= d) ? sm[t - d] : 0;
        __syncthreads();
        sm[t] += x;
        __syncthreads();
    }
    if (t < nb) bsum[t] = sm[t] - v;
}

__global__ __launch_bounds__(256) void scan_c(const int* __restrict__ excl,
    const int* __restrict__ bsum, int* __restrict__ offs, int n, int E)
{
    int g = blockIdx.x * 256 + threadIdx.x;
    if (g < n) offs[g] = excl[g] + bsum[g >> 9];
    else if (g == n) offs[n] = E;
}

__global__ __launch_bounds__(256) void scatter_k(const int* __restrict__ ei,
    const float* __restrict__ ew, const int* __restrict__ offs,
    int* __restrict__ cursor, const float* __restrict__ dinv,
    int* __restrict__ csrc, float* __restrict__ cwv, int E)
{
    int e = blockIdx.x * 256 + threadIdx.x;
    if (e >= E) return;
    int s = ei[e], d = ei[E + e];
    int pos = offs[d] + atomicAdd(&cursor[d], 1);
    csrc[pos] = s;
    cwv[pos] = ew[e] * dinv[s] * dinv[d];
}

// ---------------- W -> W^T f16 conversion ------------------------------------
__global__ __launch_bounds__(256) void cvt_w(const float* __restrict__ W,
    unsigned short* __restrict__ WT, int K, int total)
{
    int idx = blockIdx.x * 256 + threadIdx.x;
    if (idx >= total) return;
    int k = idx >> 8, n = idx & 255;
    ((_Float16*)WT)[(size_t)n * K + k] = (_Float16)W[idx];
}

// ---------------- GEMM: C[M][256](f16) = A[M][K] * B^T, f16 MFMA -------------
// Block 128x128, 4 waves (2x2 of 64x64). Per K-step(32): stage regs->LDS,
// lgkmcnt(0)+s_barrier, issue prefetch k+2, ds_read frags, 16 MFMA.
template<bool AF32>
__global__ __launch_bounds__(256, 2) void gemm_pipe(
    const void* __restrict__ Av, const unsigned short* __restrict__ BT,
    _Float16* __restrict__ C, int M, int K)
{
    constexpr int LS = 40;                       // padded LDS row stride (f16)
    __shared__ _Float16 As[2][128 * LS];
    __shared__ _Float16 Bs[2][128 * LS];
    const int t = threadIdx.x;
    const int lane = t & 63, wid = t >> 6;
    const int r = lane & 15, q = lane >> 4;
    const int n0 = blockIdx.x * 128;
    const int m0 = blockIdx.y * 128;
    const int wm = (wid >> 1) * 64, wn = (wid & 1) * 64;
    const float* Af = (const float*)Av;
    const _Float16* Ah = (const _Float16*)Av;

    // A coalesced staging coords (per thread)
    //  fp32: 4 chunks: rows it*32 + (t>>3), kc = (t&7)*4  (float4)
    //  f16 : 2 chunks: rows it*64 + (t>>2), kc = (t&3)*8  (f16x8)
    int rowA32[4], rowA16[2];
#pragma unroll
    for (int it = 0; it < 4; ++it) {
        int m = it * 32 + (t >> 3);
        int gm = m0 + m; if (gm >= M) gm = M - 1;
        rowA32[it] = gm;
    }
#pragma unroll
    for (int it = 0; it < 2; ++it) {
        int m = it * 64 + (t >> 2);
        int gm = m0 + m; if (gm >= M) gm = M - 1;
        rowA16[it] = gm;
    }
    const int kcA32 = (t & 7) << 2;
    const int kcA16 = (t & 3) << 3;
    // B: 2 chunks: cols rd*64 + (t>>2), kc = (t&3)*8 (f16x8)
    const int nB = (t >> 2) & 63;                // col within 64-group
    const int kcB = (t & 3) << 3;

    f32x4 acc[4][4];
#pragma unroll
    for (int i = 0; i < 4; ++i)
#pragma unroll
        for (int j = 0; j < 4; ++j) acc[i][j] = (f32x4){0.f, 0.f, 0.f, 0.f};

    f32x4 apre[2][4][2];   // [slot][it][2x float4]  (fp32 path: 4 rows x 8 k)
    f16x8 aph[2][2];       // [slot][it]             (f16 path)
    f16x8 bpre[2][2];      // [slot][rd]

    const int T = K >> 5;  // 32 (K=1024) or 8 (K=256), always even

#define G_ISSUE_A(kt, p)                                                        \
    {                                                                           \
        if constexpr (AF32) {                                                   \
            _Pragma("unroll")                                                   \
            for (int it = 0; it < 4; ++it) {                                    \
                const float* g = Af + (size_t)rowA32[it] * K + ((kt) << 5) + kcA32; \
                apre[p][it][0] = *(const f32x4*)g;                              \
            }                                                                   \
        } else {                                                                \
            _Pragma("unroll")                                                   \
            for (int it = 0; it < 2; ++it)                                      \
                aph[p][it] = *(const f16x8*)(Ah + (size_t)rowA16[it] * K + ((kt) << 5) + kcA16); \
        }                                                                       \
    }

#define G_ISSUE_B(kt, p)                                                        \
    {                                                                           \
        _Pragma("unroll")                                                       \
        for (int rd = 0; rd < 2; ++rd)                                          \
            bpre[p][rd] = *(const f16x8*)((const _Float16*)BT +                 \
                (size_t)(n0 + rd * 64 + nB) * K + ((kt) << 5) + kcB);           \
    }

#define G_STAGE(p)                                                              \
    {                                                                           \
        if constexpr (AF32) {                                                   \
            _Pragma("unroll")                                                   \
            for (int it = 0; it < 4; ++it) {                                    \
                int m = it * 32 + (t >> 3);                                     \
                f16x4 hv;                                                       \
                hv.x = (_Float16)apre[p][it][0].x;                              \
                hv.y = (_Float16)apre[p][it][0].y;                              \
                hv.z = (_Float16)apre[p][it][0].z;                              \
                hv.w = (_Float16)apre[p][it][0].w;                              \
                *(f16x4*)(&As[p][0] + m * LS + kcA32) = hv;                     \
            }                                                                   \
        } else {                                                                \
            _Pragma("unroll")                                                   \
            for (int it = 0; it < 2; ++it) {                                    \
                int m = it * 64 + (t >> 2);                                     \
                *(f16x8*)(&As[p][0] + m * LS + kcA16) = aph[p][it];             \
            }                                                                   \
        }                                                                       \
        _Pragma("unroll")                                                       \
        for (int rd = 0; rd < 2; ++rd) {                                        \
            int n = rd * 64 + (t >> 2);                                         \
            *(f16x8*)(&Bs[p][0] + n * LS + kcB) = bpre[p][rd];                  \
        }                                                                       \
    }

    // fp32 path loads 8 k-floats as 2x f32x4? No: one f32x4 covers kc..kc+3 only;
    // second half of the 32-k slab comes from threads with different (t&7).
    // (coords above already tile the full 128x32 slab across 1024 thread-chunks.)

#define G_BODY(kk, p)                                                           \
    {                                                                           \
        G_STAGE(p);                                                             \
        asm volatile("s_waitcnt lgkmcnt(0)" ::: "memory");                      \
        __builtin_amdgcn_s_barrier();                                           \
        __builtin_amdgcn_sched_barrier(0);                                      \
        if ((kk) + 2 < T) { G_ISSUE_A((kk) + 2, p); G_ISSUE_B((kk) + 2, p); }   \
        __builtin_amdgcn_sched_barrier(0);                                      \
        f16x8 af[4], bf[4];                                                     \
        _Pragma("unroll")                                                       \
        for (int i = 0; i < 4; ++i)                                             \
            af[i] = *(const f16x8*)(&As[p][0] + (wm + i * 16 + r) * LS + q * 8); \
        _Pragma("unroll")                                                       \
        for (int j = 0; j < 4; ++j)                                             \
            bf[j] = *(const f16x8*)(&Bs[p][0] + (wn + j * 16 + r) * LS + q * 8); \
        _Pragma("unroll")                                                       \
        for (int i = 0; i < 4; ++i)                                             \
            _Pragma("unroll")                                                   \
            for (int j = 0; j < 4; ++j)                                         \
                acc[i][j] = __builtin_amdgcn_mfma_f32_16x16x32_f16(af[i], bf[j], acc[i][j], 0, 0, 0); \
        __builtin_amdgcn_sched_barrier(0);                                      \
    }

    G_ISSUE_A(0, 0); G_ISSUE_B(0, 0);
    G_ISSUE_A(1, 1); G_ISSUE_B(1, 1);

    for (int k = 0; k < T; k += 2) {
        G_BODY(k, 0);
        G_BODY(k + 1, 1);
    }

    // epilogue: D[row = q*4+reg][col = j*16+r] per 16x16 tile
#pragma unroll
    for (int i = 0; i < 4; ++i) {
#pragma unroll
        for (int reg = 0; reg < 4; ++reg) {
            int m = m0 + wm + i * 16 + q * 4 + reg;
            if (m < M) {
                _Float16* cp = C + (size_t)m * 256 + (n0 + wn + r);
#pragma unroll
                for (int j = 0; j < 4; ++j) cp[j * 16] = (_Float16)acc[i][j][reg];
            }
        }
    }
#undef G_ISSUE_A
#undef G_ISSUE_B
#undef G_STAGE
#undef G_BODY
}

// ---------------- aggregation: out = relu(A_hat @ h + b), f16 in/out ---------
__global__ __launch_bounds__(256) void agg_relu(
    const _Float16* __restrict__ h, const int* __restrict__ roff,
    const int* __restrict__ csrc, const float* __restrict__ cwv,
    const float* __restrict__ dinv, const float* __restrict__ bias,
    _Float16* __restrict__ out, int n)
{
    const int lane = threadIdx.x & 63, wid = threadIdx.x >> 6;
    const int i = blockIdx.x * 4 + wid;
    if (i >= n) return;
    const int c = lane << 2;
    const float di = dinv[i];
    const float sw = di * di;
    const f16x4 hv = *(const f16x4*)(h + (size_t)i * 256 + c);
    float a0 = sw * (float)hv.x, a1 = sw * (float)hv.y;
    float a2 = sw * (float)hv.z, a3 = sw * (float)hv.w;
    float b0 = 0.f, b1 = 0.f, b2 = 0.f, b3 = 0.f;
    float c0 = 0.f, c1 = 0.f, c2 = 0.f, c3 = 0.f;
    float d0 = 0.f, d1 = 0.f, d2 = 0.f, d3 = 0.f;
    const int p0 = roff[i], pe = roff[i + 1];
    for (int base = p0; base < pe; base += 64) {
        int lim = pe - base; if (lim > 64) lim = 64;
        int sv = 0; float wv = 0.f;
        if (lane < lim) { sv = csrc[base + lane]; wv = cwv[base + lane]; }
        int j = 0;
        for (; j + 3 < lim; j += 4) {
            int s0 = __shfl(sv, j),     s1 = __shfl(sv, j + 1);
            int s2 = __shfl(sv, j + 2), s3 = __shfl(sv, j + 3);
            float w0 = __shfl(wv, j),     w1 = __shfl(wv, j + 1);
            float w2 = __shfl(wv, j + 2), w3 = __shfl(wv, j + 3);
            f16x4 v0 = *(const f16x4*)(h + (size_t)s0 * 256 + c);
            f16x4 v1 = *(const f16x4*)(h + (size_t)s1 * 256 + c);
            f16x4 v2 = *(const f16x4*)(h + (size_t)s2 * 256 + c);
            f16x4 v3 = *(const f16x4*)(h + (size_t)s3 * 256 + c);
            a0 += w0 * (float)v0.x; a1 += w0 * (float)v0.y;
            a2 += w0 * (float)v0.z; a3 += w0 * (float)v0.w;
            b0 += w1 * (float)v1.x; b1 += w1 * (float)v1.y;
            b2 += w1 * (float)v1.z; b3 += w1 * (float)v1.w;
            c0 += w2 * (float)v2.x; c1 += w2 * (float)v2.y;
            c2 += w2 * (float)v2.z; c3 += w2 * (float)v2.w;
            d0 += w3 * (float)v3.x; d1 += w3 * (float)v3.y;
            d2 += w3 * (float)v3.z; d3 += w3 * (float)v3.w;
        }
        for (; j < lim; ++j) {
            int s0 = __shfl(sv, j);
            float w0 = __shfl(wv, j);
            f16x4 v0 = *(const f16x4*)(h + (size_t)s0 * 256 + c);
            a0 += w0 * (float)v0.x; a1 += w0 * (float)v0.y;
            a2 += w0 * (float)v0.z; a3 += w0 * (float)v0.w;
        }
    }
    const float4 bb = *(const float4*)(bias + c);
    f16x4 o;
    o.x = (_Float16)fmaxf(a0 + b0 + c0 + d0 + bb.x, 0.f);
    o.y = (_Float16)fmaxf(a1 + b1 + c1 + d1 + bb.y, 0.f);
    o.z = (_Float16)fmaxf(a2 + b2 + c2 + d2 + bb.z, 0.f);
    o.w = (_Float16)fmaxf(a3 + b3 + c3 + d3 + bb.w, 0.f);
    *(f16x4*)(out + (size_t)i * 256 + c) = o;
}

// ---------------- BatchNorm stats (per-column over rows), f16 in -------------
__global__ __launch_bounds__(256) void bn_stats(const _Float16* __restrict__ h,
    float* __restrict__ bnsum, float* __restrict__ bnsq, int n)
{
    const int t = threadIdx.x;
    float s = 0.f, s2 = 0.f;
    for (int r = blockIdx.x; r < n; r += gridDim.x) {
        float v = (float)h[(size_t)r * 256 + t];
        s += v; s2 += v * v;
    }
    atomicAdd(&bnsum[t], s);
    atomicAdd(&bnsq[t], s2);
}

__global__ __launch_bounds__(256) void bn_params(const float* __restrict__ bnsum,
    const float* __restrict__ bnsq, const float* __restrict__ gamma,
    const float* __restrict__ beta, float* __restrict__ scale,
    float* __restrict__ shift, int n)
{
    int t = threadIdx.x;
    float mu = bnsum[t] / (float)n;
    float var = bnsq[t] / (float)n - mu * mu;
    float sc = gamma[t] * rsqrtf(var + 1e-5f);
    scale[t] = sc;
    shift[t] = beta[t] - mu * sc;
}

// ---------------- fused BN affine + LayerNorm, f16 in / fp32 out -------------
__global__ __launch_bounds__(256) void bn_ln(const _Float16* __restrict__ h,
    const float* __restrict__ scale, const float* __restrict__ shift,
    const float* __restrict__ lng, const float* __restrict__ lnb,
    float* __restrict__ out, int n)
{
    const int lane = threadIdx.x & 63, wid = threadIdx.x >> 6;
    const int i = blockIdx.x * 4 + wid;
    if (i >= n) return;
    const int c = lane << 2;
    const f16x4 v = *(const f16x4*)(h + (size_t)i * 256 + c);
    const float4 sc = *(const float4*)(scale + c);
    const float4 sh = *(const float4*)(shift + c);
    float y0 = (float)v.x * sc.x + sh.x;
    float y1 = (float)v.y * sc.y + sh.y;
    float y2 = (float)v.z * sc.z + sh.z;
    float y3 = (float)v.w * sc.w + sh.w;
    float ps = y0 + y1 + y2 + y3;
    float ps2 = y0 * y0 + y1 * y1 + y2 * y2 + y3 * y3;
#pragma unroll
    for (int off = 32; off > 0; off >>= 1) {
        ps += __shfl_down(ps, off);
        ps2 += __shfl_down(ps2, off);
    }
    ps = __shfl(ps, 0);
    ps2 = __shfl(ps2, 0);
    const float mu = ps * (1.f / 256.f);
    const float var = ps2 * (1.f / 256.f) - mu * mu;
    const float rs = rsqrtf(var + 1e-5f);
    const float4 g = *(const float4*)(lng + c);
    const float4 bb = *(const float4*)(lnb + c);
    float4 o;
    o.x = (y0 - mu) * rs * g.x + bb.x;
    o.y = (y1 - mu) * rs * g.y + bb.y;
    o.z = (y2 - mu) * rs * g.z + bb.z;
    o.w = (y3 - mu) * rs * g.w + bb.w;
    *(float4*)(out + (size_t)i * 256 + c) = o;
}

// ---------------- launcher ---------------------------------------------------
extern "C" void kernel_launch(void* const* d_in, const int* in_sizes, int n_in,
                              void* d_out, int out_size, void* d_ws, size_t ws_size,
                              hipStream_t stream)
{
    const float* x   = (const float*)d_in[0];
    const int*   ei  = (const int*)d_in[1];
    const float* ew  = (const float*)d_in[2];
    const float* W1  = (const float*)d_in[3];
    const float* b1  = (const float*)d_in[4];
    const float* W2  = (const float*)d_in[5];
    const float* b2  = (const float*)d_in[6];
    const float* bng = (const float*)d_in[7];
    const float* bnb = (const float*)d_in[8];
    const float* lng = (const float*)d_in[9];
    const float* lnb = (const float*)d_in[10];
    float* out = (float*)d_out;

    const int N = NN;
    const int E = in_sizes[2];

    char* ws = (char*)d_ws;
    size_t o = 0;
    auto alloc = [&](size_t b) -> char* {
        char* p = ws + o;
        o = (o + b + 255) & ~(size_t)255;
        return p;
    };
    _Float16* h1  = (_Float16*)alloc((size_t)N * NH * 2);   // GEMM out (reused for h2)
    _Float16* h1a = (_Float16*)alloc((size_t)N * NH * 2);
    _Float16* h2a = (_Float16*)alloc((size_t)N * NH * 2);
    unsigned short* W1T = (unsigned short*)alloc((size_t)NH * NF * 2);
    unsigned short* W2T = (unsigned short*)alloc((size_t)NH * NH * 2);
    int*   csrc = (int*)alloc((size_t)E * 4);
    float* cwv  = (float*)alloc((size_t)E * 4);
    int*   offs = (int*)alloc((size_t)(N + 1) * 4);
    int*   excl = (int*)alloc((size_t)N * 4);
    int*   bsum = (int*)alloc(512);
    float* dinv = (float*)alloc((size_t)N * 4);
    float* bnscale = (float*)alloc(NH * 4);
    float* bnshift = (float*)alloc(NH * 4);
    char* zbase = ws + o;
    unsigned long long* dc = (unsigned long long*)alloc((size_t)N * 8);
    int*   cursor = (int*)alloc((size_t)N * 4);
    float* bnsum  = (float*)alloc(NH * 4);
    float* bnsq   = (float*)alloc(NH * 4);
    size_t zbytes = (size_t)((ws + o) - zbase);
    (void)hipMemsetAsync(zbase, 0, zbytes, stream);

    cvt_w<<<(NF * NH + 255) / 256, 256, 0, stream>>>(W1, W1T, NF, NF * NH);
    cvt_w<<<(NH * NH + 255) / 256, 256, 0, stream>>>(W2, W2T, NH, NH * NH);
    deg_count<<<(E + 255) / 256, 256, 0, stream>>>(ei, ew, dc, E);
    dinv_k<<<(N + 255) / 256, 256, 0, stream>>>(dc, dinv, N);
    scan_a<<<(N + 511) / 512, 512, 0, stream>>>(dc, excl, bsum, N);
    scan_b<<<1, 128, 0, stream>>>(bsum, (N + 511) / 512);
    scan_c<<<(N + 1 + 255) / 256, 256, 0, stream>>>(excl, bsum, offs, N, E);
    scatter_k<<<(E + 255) / 256, 256, 0, stream>>>(ei, ew, offs, cursor, dinv, csrc, cwv, E);

    dim3 gg(2, (N + 127) / 128);
    gemm_pipe<true><<<gg, 256, 0, stream>>>(x, W1T, h1, N, NF);
    agg_relu<<<(N + 3) / 4, 256, 0, stream>>>(h1, offs, csrc, cwv, dinv, b1, h1a, N);
    gemm_pipe<false><<<gg, 256, 0, stream>>>(h1a, W2T, h1, N, NH);
    agg_relu<<<(N + 3) / 4, 256, 0, stream>>>(h1, offs, csrc, cwv, dinv, b2, h2a, N);

    bn_stats<<<256, 256, 0, stream>>>(h2a, bnsum, bnsq, N);
    bn_params<<<1, 256, 0, stream>>>(bnsum, bnsq, bng, bnb, bnscale, bnshift, N);
    bn_ln<<<(N + 3) / 4, 256, 0, stream>>>(h2a, bnscale, bnshift, lng, lnb, out, N);
}

// Round 5
// 633.360 us; speedup vs baseline: 1.2654x; 1.0196x over previous
//
#include <hip/hip_runtime.h>

// GCN pipeline on MI355X, round 6:
//   deg/dinv(packed u64 atomic) -> CSR -> GEMM1(reg-staged dbuf, padded LDS,
//   raw-barrier pipeline) -> agg+relu(8-deep) -> GEMM2(same) -> agg+relu
//   -> BN stats(vectorized) -> fused BN+LN -> out
// R5 changes: agg_relu gather pipeline 4->8 deep (latency chain was the theory-
// predicted limiter); bn_stats vectorized f16x4 + LDS cross-group reduce;
// cvt_w LDS-tiled transpose (coalesced global R/W). GEMM unchanged from R4 win.

typedef __attribute__((ext_vector_type(4))) float f32x4;
typedef __attribute__((ext_vector_type(8))) _Float16 f16x8;
typedef __attribute__((ext_vector_type(4))) _Float16 f16x4;

#define NN 50000
#define NF 1024
#define NH 256

// ---------------- degree+count in ONE u64 atomic per edge --------------------
// dc[d] accumulates: (count << 40) | round(w * 2^24). deg < ~64 -> low40 < 2^30.
__global__ __launch_bounds__(256) void deg_count(const int* __restrict__ ei,
    const float* __restrict__ ew, unsigned long long* __restrict__ dc, int E)
{
    int e = blockIdx.x * 256 + threadIdx.x;
    if (e >= E) return;
    int d = ei[E + e];
    unsigned long long pack = (1ull << 40) |
        (unsigned long long)(unsigned int)(ew[e] * 16777216.0f + 0.5f);
    atomicAdd(&dc[d], pack);
}

__global__ __launch_bounds__(256) void dinv_k(const unsigned long long* __restrict__ dc,
    float* __restrict__ dinv, int n)
{
    int i = blockIdx.x * 256 + threadIdx.x;
    if (i < n) {
        float deg = (float)(dc[i] & 0xFFFFFFFFFFull) * (1.0f / 16777216.0f);
        dinv[i] = rsqrtf(deg + 1.0f);   // +1 = self-loop weight
    }
}

// ---------------- CSR build: 3-kernel exclusive scan + scatter ---------------
__global__ __launch_bounds__(512) void scan_a(const unsigned long long* __restrict__ dc,
    int* __restrict__ excl, int* __restrict__ bsum, int n)
{
    __shared__ int sm[512];
    int t = threadIdx.x, g = blockIdx.x * 512 + t;
    int v = (g < n) ? (int)(dc[g] >> 40) : 0;
    sm[t] = v;
    __syncthreads();
    for (int d = 1; d < 512; d <<= 1) {
        int x = (t >= d) ? sm[t - d] : 0;
        __syncthreads();
        sm[t] += x;
        __syncthreads();
    }
    if (g < n) excl[g] = sm[t] - v;
    if (t == 511) bsum[blockIdx.x] = sm[511];
}

__global__ __launch_bounds__(128) void scan_b(int* __restrict__ bsum, int nb)
{
    __shared__ int sm[128];
    int t = threadIdx.x;
    int v = (t < nb) ? bsum[t] : 0;
    sm[t] = v;
    __syncthreads();
    for (int d = 1; d < 128; d <<= 1) {
        int x = (t >= d) ? sm[t - d] : 0;
        __syncthreads();
        sm[t] += x;
        __syncthreads();
    }
    if (t < nb) bsum[t] = sm[t] - v;
}

__global__ __launch_bounds__(256) void scan_c(const int* __restrict__ excl,
    const int* __restrict__ bsum, int* __restrict__ offs, int n, int E)
{
    int g = blockIdx.x * 256 + threadIdx.x;
    if (g < n) offs[g] = excl[g] + bsum[g >> 9];
    else if (g == n) offs[n] = E;
}

__global__ __launch_bounds__(256) void scatter_k(const int* __restrict__ ei,
    const float* __restrict__ ew, const int* __restrict__ offs,
    int* __restrict__ cursor, const float* __restrict__ dinv,
    int* __restrict__ csrc, float* __restrict__ cwv, int E)
{
    int e = blockIdx.x * 256 + threadIdx.x;
    if (e >= E) return;
    int s = ei[e], d = ei[E + e];
    int pos = offs[d] + atomicAdd(&cursor[d], 1);
    csrc[pos] = s;
    cwv[pos] = ew[e] * dinv[s] * dinv[d];
}

// ---------------- W -> W^T f16, LDS-tiled 64x64 transpose --------------------
// W [K][256] f32 row-major -> WT [256][K] f16. Coalesced float4 reads,
// coalesced f16x8 writes; transpose via LDS tile (stride 72 f16 keeps the
// f16x8 reads 16B-aligned; write conflicts negligible at this size).
__global__ __launch_bounds__(256) void cvt_w(const float* __restrict__ W,
    unsigned short* __restrict__ WT, int K)
{
    __shared__ _Float16 tile[64][72];
    const int t = threadIdx.x;
    const int k0 = blockIdx.x << 6, n0 = blockIdx.y << 6;
#pragma unroll
    for (int it = 0; it < 4; ++it) {
        int idx = it * 256 + t;          // 0..1023 covers 64k x 16 float4
        int kk = idx >> 4;               // 0..63
        int nn = (idx & 15) << 2;        // 0..60
        float4 v = *(const float4*)(W + (size_t)(k0 + kk) * 256 + n0 + nn);
        tile[nn + 0][kk] = (_Float16)v.x;
        tile[nn + 1][kk] = (_Float16)v.y;
        tile[nn + 2][kk] = (_Float16)v.z;
        tile[nn + 3][kk] = (_Float16)v.w;
    }
    __syncthreads();
#pragma unroll
    for (int it = 0; it < 2; ++it) {
        int idx = it * 256 + t;          // 0..511 covers 64n x 8 f16x8
        int nn = idx >> 3;               // 0..63
        int kk = (idx & 7) << 3;         // 0..56
        *(f16x8*)((_Float16*)WT + (size_t)(n0 + nn) * K + k0 + kk) =
            *(const f16x8*)&tile[nn][kk];
    }
}

// ---------------- GEMM: C[M][256](f16) = A[M][K] * B^T, f16 MFMA -------------
// Block 128x128, 4 waves (2x2 of 64x64). Per K-step(32): stage regs->LDS,
// lgkmcnt(0)+s_barrier, issue prefetch k+2, ds_read frags, 16 MFMA.
template<bool AF32>
__global__ __launch_bounds__(256, 2) void gemm_pipe(
    const void* __restrict__ Av, const unsigned short* __restrict__ BT,
    _Float16* __restrict__ C, int M, int K)
{
    constexpr int LS = 40;                       // padded LDS row stride (f16)
    __shared__ _Float16 As[2][128 * LS];
    __shared__ _Float16 Bs[2][128 * LS];
    const int t = threadIdx.x;
    const int lane = t & 63, wid = t >> 6;
    const int r = lane & 15, q = lane >> 4;
    const int n0 = blockIdx.x * 128;
    const int m0 = blockIdx.y * 128;
    const int wm = (wid >> 1) * 64, wn = (wid & 1) * 64;
    const float* Af = (const float*)Av;
    const _Float16* Ah = (const _Float16*)Av;

    int rowA32[4], rowA16[2];
#pragma unroll
    for (int it = 0; it < 4; ++it) {
        int m = it * 32 + (t >> 3);
        int gm = m0 + m; if (gm >= M) gm = M - 1;
        rowA32[it] = gm;
    }
#pragma unroll
    for (int it = 0; it < 2; ++it) {
        int m = it * 64 + (t >> 2);
        int gm = m0 + m; if (gm >= M) gm = M - 1;
        rowA16[it] = gm;
    }
    const int kcA32 = (t & 7) << 2;
    const int kcA16 = (t & 3) << 3;
    const int nB = (t >> 2) & 63;
    const int kcB = (t & 3) << 3;

    f32x4 acc[4][4];
#pragma unroll
    for (int i = 0; i < 4; ++i)
#pragma unroll
        for (int j = 0; j < 4; ++j) acc[i][j] = (f32x4){0.f, 0.f, 0.f, 0.f};

    f32x4 apre[2][4][2];
    f16x8 aph[2][2];
    f16x8 bpre[2][2];

    const int T = K >> 5;

#define G_ISSUE_A(kt, p)                                                        \
    {                                                                           \
        if constexpr (AF32) {                                                   \
            _Pragma("unroll")                                                   \
            for (int it = 0; it < 4; ++it) {                                    \
                const float* g = Af + (size_t)rowA32[it] * K + ((kt) << 5) + kcA32; \
                apre[p][it][0] = *(const f32x4*)g;                              \
            }                                                                   \
        } else {                                                                \
            _Pragma("unroll")                                                   \
            for (int it = 0; it < 2; ++it)                                      \
                aph[p][it] = *(const f16x8*)(Ah + (size_t)rowA16[it] * K + ((kt) << 5) + kcA16); \
        }                                                                       \
    }

#define G_ISSUE_B(kt, p)                                                        \
    {                                                                           \
        _Pragma("unroll")                                                       \
        for (int rd = 0; rd < 2; ++rd)                                          \
            bpre[p][rd] = *(const f16x8*)((const _Float16*)BT +                 \
                (size_t)(n0 + rd * 64 + nB) * K + ((kt) << 5) + kcB);           \
    }

#define G_STAGE(p)                                                              \
    {                                                                           \
        if constexpr (AF32) {                                                   \
            _Pragma("unroll")                                                   \
            for (int it = 0; it < 4; ++it) {                                    \
                int m = it * 32 + (t >> 3);                                     \
                f16x4 hv;                                                       \
                hv.x = (_Float16)apre[p][it][0].x;                              \
                hv.y = (_Float16)apre[p][it][0].y;                              \
                hv.z = (_Float16)apre[p][it][0].z;                              \
                hv.w = (_Float16)apre[p][it][0].w;                              \
                *(f16x4*)(&As[p][0] + m * LS + kcA32) = hv;                     \
            }                                                                   \
        } else {                                                                \
            _Pragma("unroll")                                                   \
            for (int it = 0; it < 2; ++it) {                                    \
                int m = it * 64 + (t >> 2);                                     \
                *(f16x8*)(&As[p][0] + m * LS + kcA16) = aph[p][it];             \
            }                                                                   \
        }                                                                       \
        _Pragma("unroll")                                                       \
        for (int rd = 0; rd < 2; ++rd) {                                        \
            int n = rd * 64 + (t >> 2);                                         \
            *(f16x8*)(&Bs[p][0] + n * LS + kcB) = bpre[p][rd];                  \
        }                                                                       \
    }

#define G_BODY(kk, p)                                                           \
    {                                                                           \
        G_STAGE(p);                                                             \
        asm volatile("s_waitcnt lgkmcnt(0)" ::: "memory");                      \
        __builtin_amdgcn_s_barrier();                                           \
        __builtin_amdgcn_sched_barrier(0);                                      \
        if ((kk) + 2 < T) { G_ISSUE_A((kk) + 2, p); G_ISSUE_B((kk) + 2, p); }   \
        __builtin_amdgcn_sched_barrier(0);                                      \
        f16x8 af[4], bf[4];                                                     \
        _Pragma("unroll")                                                       \
        for (int i = 0; i < 4; ++i)                                             \
            af[i] = *(const f16x8*)(&As[p][0] + (wm + i * 16 + r) * LS + q * 8); \
        _Pragma("unroll")                                                       \
        for (int j = 0; j < 4; ++j)                                             \
            bf[j] = *(const f16x8*)(&Bs[p][0] + (wn + j * 16 + r) * LS + q * 8); \
        _Pragma("unroll")                                                       \
        for (int i = 0; i < 4; ++i)                                             \
            _Pragma("unroll")                                                   \
            for (int j = 0; j < 4; ++j)                                         \
                acc[i][j] = __builtin_amdgcn_mfma_f32_16x16x32_f16(af[i], bf[j], acc[i][j], 0, 0, 0); \
        __builtin_amdgcn_sched_barrier(0);                                      \
    }

    G_ISSUE_A(0, 0); G_ISSUE_B(0, 0);
    G_ISSUE_A(1, 1); G_ISSUE_B(1, 1);

    for (int k = 0; k < T; k += 2) {
        G_BODY(k, 0);
        G_BODY(k + 1, 1);
    }

#pragma unroll
    for (int i = 0; i < 4; ++i) {
#pragma unroll
        for (int reg = 0; reg < 4; ++reg) {
            int m = m0 + wm + i * 16 + q * 4 + reg;
            if (m < M) {
                _Float16* cp = C + (size_t)m * 256 + (n0 + wn + r);
#pragma unroll
                for (int j = 0; j < 4; ++j) cp[j * 16] = (_Float16)acc[i][j][reg];
            }
        }
    }
#undef G_ISSUE_A
#undef G_ISSUE_B
#undef G_STAGE
#undef G_BODY
}

// ---------------- aggregation: out = relu(A_hat @ h + b), f16 in/out ---------
// 1 wave per node; lane holds cols [4*lane, 4*lane+4). Edge metadata loaded
// cooperatively, broadcast via shfl; 8 independent gathers in flight per step.
__global__ __launch_bounds__(256) void agg_relu(
    const _Float16* __restrict__ h, const int* __restrict__ roff,
    const int* __restrict__ csrc, const float* __restrict__ cwv,
    const float* __restrict__ dinv, const float* __restrict__ bias,
    _Float16* __restrict__ out, int n)
{
    const int lane = threadIdx.x & 63, wid = threadIdx.x >> 6;
    const int i = blockIdx.x * 4 + wid;
    if (i >= n) return;
    const int c = lane << 2;
    const float di = dinv[i];
    const float sw = di * di;
    const f16x4 hv = *(const f16x4*)(h + (size_t)i * 256 + c);
    float a0 = sw * (float)hv.x, a1 = sw * (float)hv.y;
    float a2 = sw * (float)hv.z, a3 = sw * (float)hv.w;
    float b0 = 0.f, b1 = 0.f, b2 = 0.f, b3 = 0.f;
    float c0 = 0.f, c1 = 0.f, c2 = 0.f, c3 = 0.f;
    float d0 = 0.f, d1 = 0.f, d2 = 0.f, d3 = 0.f;
    const int p0 = roff[i], pe = roff[i + 1];
    for (int base = p0; base < pe; base += 64) {
        int lim = pe - base; if (lim > 64) lim = 64;
        int sv = 0; float wv = 0.f;
        if (lane < lim) { sv = csrc[base + lane]; wv = cwv[base + lane]; }
        int j = 0;
        for (; j + 7 < lim; j += 8) {
            int s0 = __shfl(sv, j),     s1 = __shfl(sv, j + 1);
            int s2 = __shfl(sv, j + 2), s3 = __shfl(sv, j + 3);
            int s4 = __shfl(sv, j + 4), s5 = __shfl(sv, j + 5);
            int s6 = __shfl(sv, j + 6), s7 = __shfl(sv, j + 7);
            float w0 = __shfl(wv, j),     w1 = __shfl(wv, j + 1);
            float w2 = __shfl(wv, j + 2), w3 = __shfl(wv, j + 3);
            float w4 = __shfl(wv, j + 4), w5 = __shfl(wv, j + 5);
            float w6 = __shfl(wv, j + 6), w7 = __shfl(wv, j + 7);
            f16x4 v0 = *(const f16x4*)(h + (size_t)s0 * 256 + c);
            f16x4 v1 = *(const f16x4*)(h + (size_t)s1 * 256 + c);
            f16x4 v2 = *(const f16x4*)(h + (size_t)s2 * 256 + c);
            f16x4 v3 = *(const f16x4*)(h + (size_t)s3 * 256 + c);
            f16x4 v4 = *(const f16x4*)(h + (size_t)s4 * 256 + c);
            f16x4 v5 = *(const f16x4*)(h + (size_t)s5 * 256 + c);
            f16x4 v6 = *(const f16x4*)(h + (size_t)s6 * 256 + c);
            f16x4 v7 = *(const f16x4*)(h + (size_t)s7 * 256 + c);
            a0 += w0 * (float)v0.x; a1 += w0 * (float)v0.y;
            a2 += w0 * (float)v0.z; a3 += w0 * (float)v0.w;
            b0 += w1 * (float)v1.x; b1 += w1 * (float)v1.y;
            b2 += w1 * (float)v1.z; b3 += w1 * (float)v1.w;
            c0 += w2 * (float)v2.x; c1 += w2 * (float)v2.y;
            c2 += w2 * (float)v2.z; c3 += w2 * (float)v2.w;
            d0 += w3 * (float)v3.x; d1 += w3 * (float)v3.y;
            d2 += w3 * (float)v3.z; d3 += w3 * (float)v3.w;
            a0 += w4 * (float)v4.x; a1 += w4 * (float)v4.y;
            a2 += w4 * (float)v4.z; a3 += w4 * (float)v4.w;
            b0 += w5 * (float)v5.x; b1 += w5 * (float)v5.y;
            b2 += w5 * (float)v5.z; b3 += w5 * (float)v5.w;
            c0 += w6 * (float)v6.x; c1 += w6 * (float)v6.y;
            c2 += w6 * (float)v6.z; c3 += w6 * (float)v6.w;
            d0 += w7 * (float)v7.x; d1 += w7 * (float)v7.y;
            d2 += w7 * (float)v7.z; d3 += w7 * (float)v7.w;
        }
        for (; j + 1 < lim; j += 2) {
            int s0 = __shfl(sv, j), s1 = __shfl(sv, j + 1);
            float w0 = __shfl(wv, j), w1 = __shfl(wv, j + 1);
            f16x4 v0 = *(const f16x4*)(h + (size_t)s0 * 256 + c);
            f16x4 v1 = *(const f16x4*)(h + (size_t)s1 * 256 + c);
            a0 += w0 * (float)v0.x; a1 += w0 * (float)v0.y;
            a2 += w0 * (float)v0.z; a3 += w0 * (float)v0.w;
            b0 += w1 * (float)v1.x; b1 += w1 * (float)v1.y;
            b2 += w1 * (float)v1.z; b3 += w1 * (float)v1.w;
        }
        if (j < lim) {
            int s0 = __shfl(sv, j);
            float w0 = __shfl(wv, j);
            f16x4 v0 = *(const f16x4*)(h + (size_t)s0 * 256 + c);
            a0 += w0 * (float)v0.x; a1 += w0 * (float)v0.y;
            a2 += w0 * (float)v0.z; a3 += w0 * (float)v0.w;
        }
    }
    const float4 bb = *(const float4*)(bias + c);
    f16x4 o;
    o.x = (_Float16)fmaxf(a0 + b0 + c0 + d0 + bb.x, 0.f);
    o.y = (_Float16)fmaxf(a1 + b1 + c1 + d1 + bb.y, 0.f);
    o.z = (_Float16)fmaxf(a2 + b2 + c2 + d2 + bb.z, 0.f);
    o.w = (_Float16)fmaxf(a3 + b3 + c3 + d3 + bb.w, 0.f);
    *(f16x4*)(out + (size_t)i * 256 + c) = o;
}

// ---------------- BatchNorm stats (per-column over rows), f16 in -------------
// 256 blocks; block = 4 row-groups x 64 lanes; lane owns cols [4*lane,+4).
// Vectorized f16x4 loads, LDS cross-group reduce, 1 atomic per col per block.
__global__ __launch_bounds__(256) void bn_stats(const _Float16* __restrict__ h,
    float* __restrict__ bnsum, float* __restrict__ bnsq, int n)
{
    const int t = threadIdx.x, lane = t & 63, g = t >> 6;
    const int c = lane << 2;
    float s0 = 0.f, s1 = 0.f, s2 = 0.f, s3 = 0.f;
    float q0 = 0.f, q1 = 0.f, q2 = 0.f, q3 = 0.f;
    for (int r = blockIdx.x * 4 + g; r < n; r += gridDim.x * 4) {
        f16x4 v = *(const f16x4*)(h + (size_t)r * 256 + c);
        float f0 = (float)v.x, f1 = (float)v.y, f2 = (float)v.z, f3 = (float)v.w;
        s0 += f0; s1 += f1; s2 += f2; s3 += f3;
        q0 += f0 * f0; q1 += f1 * f1; q2 += f2 * f2; q3 += f3 * f3;
    }
    __shared__ float sm[4][256];
    *(float4*)&sm[g][c] = (float4){s0, s1, s2, s3};
    __syncthreads();
    if (g == 0) {
        float4 a = *(float4*)&sm[0][c], b = *(float4*)&sm[1][c];
        float4 d = *(float4*)&sm[2][c], e = *(float4*)&sm[3][c];
        atomicAdd(&bnsum[c + 0], a.x + b.x + d.x + e.x);
        atomicAdd(&bnsum[c + 1], a.y + b.y + d.y + e.y);
        atomicAdd(&bnsum[c + 2], a.z + b.z + d.z + e.z);
        atomicAdd(&bnsum[c + 3], a.w + b.w + d.w + e.w);
    }
    __syncthreads();
    *(float4*)&sm[g][c] = (float4){q0, q1, q2, q3};
    __syncthreads();
    if (g == 0) {
        float4 a = *(float4*)&sm[0][c], b = *(float4*)&sm[1][c];
        float4 d = *(float4*)&sm[2][c], e = *(float4*)&sm[3][c];
        atomicAdd(&bnsq[c + 0], a.x + b.x + d.x + e.x);
        atomicAdd(&bnsq[c + 1], a.y + b.y + d.y + e.y);
        atomicAdd(&bnsq[c + 2], a.z + b.z + d.z + e.z);
        atomicAdd(&bnsq[c + 3], a.w + b.w + d.w + e.w);
    }
}

__global__ __launch_bounds__(256) void bn_params(const float* __restrict__ bnsum,
    const float* __restrict__ bnsq, const float* __restrict__ gamma,
    const float* __restrict__ beta, float* __restrict__ scale,
    float* __restrict__ shift, int n)
{
    int t = threadIdx.x;
    float mu = bnsum[t] / (float)n;
    float var = bnsq[t] / (float)n - mu * mu;
    float sc = gamma[t] * rsqrtf(var + 1e-5f);
    scale[t] = sc;
    shift[t] = beta[t] - mu * sc;
}

// ---------------- fused BN affine + LayerNorm, f16 in / fp32 out -------------
__global__ __launch_bounds__(256) void bn_ln(const _Float16* __restrict__ h,
    const float* __restrict__ scale, const float* __restrict__ shift,
    const float* __restrict__ lng, const float* __restrict__ lnb,
    float* __restrict__ out, int n)
{
    const int lane = threadIdx.x & 63, wid = threadIdx.x >> 6;
    const int i = blockIdx.x * 4 + wid;
    if (i >= n) return;
    const int c = lane << 2;
    const f16x4 v = *(const f16x4*)(h + (size_t)i * 256 + c);
    const float4 sc = *(const float4*)(scale + c);
    const float4 sh = *(const float4*)(shift + c);
    float y0 = (float)v.x * sc.x + sh.x;
    float y1 = (float)v.y * sc.y + sh.y;
    float y2 = (float)v.z * sc.z + sh.z;
    float y3 = (float)v.w * sc.w + sh.w;
    float ps = y0 + y1 + y2 + y3;
    float ps2 = y0 * y0 + y1 * y1 + y2 * y2 + y3 * y3;
#pragma unroll
    for (int off = 32; off > 0; off >>= 1) {
        ps += __shfl_down(ps, off);
        ps2 += __shfl_down(ps2, off);
    }
    ps = __shfl(ps, 0);
    ps2 = __shfl(ps2, 0);
    const float mu = ps * (1.f / 256.f);
    const float var = ps2 * (1.f / 256.f) - mu * mu;
    const float rs = rsqrtf(var + 1e-5f);
    const float4 g = *(const float4*)(lng + c);
    const float4 bb = *(const float4*)(lnb + c);
    float4 o;
    o.x = (y0 - mu) * rs * g.x + bb.x;
    o.y = (y1 - mu) * rs * g.y + bb.y;
    o.z = (y2 - mu) * rs * g.z + bb.z;
    o.w = (y3 - mu) * rs * g.w + bb.w;
    *(float4*)(out + (size_t)i * 256 + c) = o;
}

// ---------------- launcher ---------------------------------------------------
extern "C" void kernel_launch(void* const* d_in, const int* in_sizes, int n_in,
                              void* d_out, int out_size, void* d_ws, size_t ws_size,
                              hipStream_t stream)
{
    const float* x   = (const float*)d_in[0];
    const int*   ei  = (const int*)d_in[1];
    const float* ew  = (const float*)d_in[2];
    const float* W1  = (const float*)d_in[3];
    const float* b1  = (const float*)d_in[4];
    const float* W2  = (const float*)d_in[5];
    const float* b2  = (const float*)d_in[6];
    const float* bng = (const float*)d_in[7];
    const float* bnb = (const float*)d_in[8];
    const float* lng = (const float*)d_in[9];
    const float* lnb = (const float*)d_in[10];
    float* out = (float*)d_out;

    const int N = NN;
    const int E = in_sizes[2];

    char* ws = (char*)d_ws;
    size_t o = 0;
    auto alloc = [&](size_t b) -> char* {
        char* p = ws + o;
        o = (o + b + 255) & ~(size_t)255;
        return p;
    };
    _Float16* h1  = (_Float16*)alloc((size_t)N * NH * 2);   // GEMM out (reused for h2)
    _Float16* h1a = (_Float16*)alloc((size_t)N * NH * 2);
    _Float16* h2a = (_Float16*)alloc((size_t)N * NH * 2);
    unsigned short* W1T = (unsigned short*)alloc((size_t)NH * NF * 2);
    unsigned short* W2T = (unsigned short*)alloc((size_t)NH * NH * 2);
    int*   csrc = (int*)alloc((size_t)E * 4);
    float* cwv  = (float*)alloc((size_t)E * 4);
    int*   offs = (int*)alloc((size_t)(N + 1) * 4);
    int*   excl = (int*)alloc((size_t)N * 4);
    int*   bsum = (int*)alloc(512);
    float* dinv = (float*)alloc((size_t)N * 4);
    float* bnscale = (float*)alloc(NH * 4);
    float* bnshift = (float*)alloc(NH * 4);
    char* zbase = ws + o;
    unsigned long long* dc = (unsigned long long*)alloc((size_t)N * 8);
    int*   cursor = (int*)alloc((size_t)N * 4);
    float* bnsum  = (float*)alloc(NH * 4);
    float* bnsq   = (float*)alloc(NH * 4);
    size_t zbytes = (size_t)((ws + o) - zbase);
    (void)hipMemsetAsync(zbase, 0, zbytes, stream);

    cvt_w<<<dim3(NF >> 6, 4), 256, 0, stream>>>(W1, W1T, NF);
    cvt_w<<<dim3(NH >> 6, 4), 256, 0, stream>>>(W2, W2T, NH);
    deg_count<<<(E + 255) / 256, 256, 0, stream>>>(ei, ew, dc, E);
    dinv_k<<<(N + 255) / 256, 256, 0, stream>>>(dc, dinv, N);
    scan_a<<<(N + 511) / 512, 512, 0, stream>>>(dc, excl, bsum, N);
    scan_b<<<1, 128, 0, stream>>>(bsum, (N + 511) / 512);
    scan_c<<<(N + 1 + 255) / 256, 256, 0, stream>>>(excl, bsum, offs, N, E);
    scatter_k<<<(E + 255) / 256, 256, 0, stream>>>(ei, ew, offs, cursor, dinv, csrc, cwv, E);

    dim3 gg(2, (N + 127) / 128);
    gemm_pipe<true><<<gg, 256, 0, stream>>>(x, W1T, h1, N, NF);
    agg_relu<<<(N + 3) / 4, 256, 0, stream>>>(h1, offs, csrc, cwv, dinv, b1, h1a, N);
    gemm_pipe<false><<<gg, 256, 0, stream>>>(h1a, W2T, h1, N, NH);
    agg_relu<<<(N + 3) / 4, 256, 0, stream>>>(h1, offs, csrc, cwv, dinv, b2, h2a, N);

    bn_stats<<<256, 256, 0, stream>>>(h2a, bnsum, bnsq, N);
    bn_params<<<1, 256, 0, stream>>>(bnsum, bnsq, bng, bnb, bnscale, bnshift, N);
    bn_ln<<<(N + 3) / 4, 256, 0, stream>>>(h2a, bnscale, bnshift, lng, lnb, out, N);
}

// Round 6
// 629.867 us; speedup vs baseline: 1.2725x; 1.0055x over previous
//
#include <hip/hip_runtime.h>

// GCN pipeline on MI355X, round 7:
//   deg/dinv(packed u64) -> CSR(int2 edge data) -> GEMM1(R4 pipeline, unchanged)
//   -> agg+relu(2-edges-per-gather, half-wave split) -> GEMM2 -> agg+relu
//   -> BN stats -> fused BN+LN -> out
// R6 changes: agg_relu gathers 16B/lane f16x8 (one instruction fetches TWO edge
// rows: lanes 0-31 edge j, lanes 32-63 edge j+1); split accumulators combined by
// one shfl_xor(32); zero-padded slots (w=0 -> row 0, L1-hot). Edge meta packed
// int2 (single 8B load). GEMM/BN/LN unchanged from the R4/R5 verified state.

typedef __attribute__((ext_vector_type(4))) float f32x4;
typedef __attribute__((ext_vector_type(8))) _Float16 f16x8;
typedef __attribute__((ext_vector_type(4))) _Float16 f16x4;

#define NN 50000
#define NF 1024
#define NH 256

// ---------------- degree+count in ONE u64 atomic per edge --------------------
__global__ __launch_bounds__(256) void deg_count(const int* __restrict__ ei,
    const float* __restrict__ ew, unsigned long long* __restrict__ dc, int E)
{
    int e = blockIdx.x * 256 + threadIdx.x;
    if (e >= E) return;
    int d = ei[E + e];
    unsigned long long pack = (1ull << 40) |
        (unsigned long long)(unsigned int)(ew[e] * 16777216.0f + 0.5f);
    atomicAdd(&dc[d], pack);
}

__global__ __launch_bounds__(256) void dinv_k(const unsigned long long* __restrict__ dc,
    float* __restrict__ dinv, int n)
{
    int i = blockIdx.x * 256 + threadIdx.x;
    if (i < n) {
        float deg = (float)(dc[i] & 0xFFFFFFFFFFull) * (1.0f / 16777216.0f);
        dinv[i] = rsqrtf(deg + 1.0f);   // +1 = self-loop weight
    }
}

// ---------------- CSR build: 3-kernel exclusive scan + scatter ---------------
__global__ __launch_bounds__(512) void scan_a(const unsigned long long* __restrict__ dc,
    int* __restrict__ excl, int* __restrict__ bsum, int n)
{
    __shared__ int sm[512];
    int t = threadIdx.x, g = blockIdx.x * 512 + t;
    int v = (g < n) ? (int)(dc[g] >> 40) : 0;
    sm[t] = v;
    __syncthreads();
    for (int d = 1; d < 512; d <<= 1) {
        int x = (t >= d) ? sm[t - d] : 0;
        __syncthreads();
        sm[t] += x;
        __syncthreads();
    }
    if (g < n) excl[g] = sm[t] - v;
    if (t == 511) bsum[blockIdx.x] = sm[511];
}

__global__ __launch_bounds__(128) void scan_b(int* __restrict__ bsum, int nb)
{
    __shared__ int sm[128];
    int t = threadIdx.x;
    int v = (t < nb) ? bsum[t] : 0;
    sm[t] = v;
    __syncthreads();
    for (int d = 1; d < 128; d <<= 1) {
        int x = (t >= d) ? sm[t - d] : 0;
        __syncthreads();
        sm[t] += x;
        __syncthreads();
    }
    if (t < nb) bsum[t] = sm[t] - v;
}

__global__ __launch_bounds__(256) void scan_c(const int* __restrict__ excl,
    const int* __restrict__ bsum, int* __restrict__ offs, int n, int E)
{
    int g = blockIdx.x * 256 + threadIdx.x;
    if (g < n) offs[g] = excl[g] + bsum[g >> 9];
    else if (g == n) offs[n] = E;
}

__global__ __launch_bounds__(256) void scatter_k(const int* __restrict__ ei,
    const float* __restrict__ ew, const int* __restrict__ offs,
    int* __restrict__ cursor, const float* __restrict__ dinv,
    int2* __restrict__ edata, int E)
{
    int e = blockIdx.x * 256 + threadIdx.x;
    if (e >= E) return;
    int s = ei[e], d = ei[E + e];
    int pos = offs[d] + atomicAdd(&cursor[d], 1);
    float w = ew[e] * dinv[s] * dinv[d];
    edata[pos] = make_int2(s, __float_as_int(w));
}

// ---------------- W -> W^T f16, LDS-tiled 64x64 transpose --------------------
__global__ __launch_bounds__(256) void cvt_w(const float* __restrict__ W,
    unsigned short* __restrict__ WT, int K)
{
    __shared__ _Float16 tile[64][72];
    const int t = threadIdx.x;
    const int k0 = blockIdx.x << 6, n0 = blockIdx.y << 6;
#pragma unroll
    for (int it = 0; it < 4; ++it) {
        int idx = it * 256 + t;
        int kk = idx >> 4;
        int nn = (idx & 15) << 2;
        float4 v = *(const float4*)(W + (size_t)(k0 + kk) * 256 + n0 + nn);
        tile[nn + 0][kk] = (_Float16)v.x;
        tile[nn + 1][kk] = (_Float16)v.y;
        tile[nn + 2][kk] = (_Float16)v.z;
        tile[nn + 3][kk] = (_Float16)v.w;
    }
    __syncthreads();
#pragma unroll
    for (int it = 0; it < 2; ++it) {
        int idx = it * 256 + t;
        int nn = idx >> 3;
        int kk = (idx & 7) << 3;
        *(f16x8*)((_Float16*)WT + (size_t)(n0 + nn) * K + k0 + kk) =
            *(const f16x8*)&tile[nn][kk];
    }
}

// ---------------- GEMM: C[M][256](f16) = A[M][K] * B^T, f16 MFMA -------------
// (unchanged from R4 verified win)
template<bool AF32>
__global__ __launch_bounds__(256, 2) void gemm_pipe(
    const void* __restrict__ Av, const unsigned short* __restrict__ BT,
    _Float16* __restrict__ C, int M, int K)
{
    constexpr int LS = 40;
    __shared__ _Float16 As[2][128 * LS];
    __shared__ _Float16 Bs[2][128 * LS];
    const int t = threadIdx.x;
    const int lane = t & 63, wid = t >> 6;
    const int r = lane & 15, q = lane >> 4;
    const int n0 = blockIdx.x * 128;
    const int m0 = blockIdx.y * 128;
    const int wm = (wid >> 1) * 64, wn = (wid & 1) * 64;
    const float* Af = (const float*)Av;
    const _Float16* Ah = (const _Float16*)Av;

    int rowA32[4], rowA16[2];
#pragma unroll
    for (int it = 0; it < 4; ++it) {
        int m = it * 32 + (t >> 3);
        int gm = m0 + m; if (gm >= M) gm = M - 1;
        rowA32[it] = gm;
    }
#pragma unroll
    for (int it = 0; it < 2; ++it) {
        int m = it * 64 + (t >> 2);
        int gm = m0 + m; if (gm >= M) gm = M - 1;
        rowA16[it] = gm;
    }
    const int kcA32 = (t & 7) << 2;
    const int kcA16 = (t & 3) << 3;
    const int nB = (t >> 2) & 63;
    const int kcB = (t & 3) << 3;

    f32x4 acc[4][4];
#pragma unroll
    for (int i = 0; i < 4; ++i)
#pragma unroll
        for (int j = 0; j < 4; ++j) acc[i][j] = (f32x4){0.f, 0.f, 0.f, 0.f};

    f32x4 apre[2][4][2];
    f16x8 aph[2][2];
    f16x8 bpre[2][2];

    const int T = K >> 5;

#define G_ISSUE_A(kt, p)                                                        \
    {                                                                           \
        if constexpr (AF32) {                                                   \
            _Pragma("unroll")                                                   \
            for (int it = 0; it < 4; ++it) {                                    \
                const float* g = Af + (size_t)rowA32[it] * K + ((kt) << 5) + kcA32; \
                apre[p][it][0] = *(const f32x4*)g;                              \
            }                                                                   \
        } else {                                                                \
            _Pragma("unroll")                                                   \
            for (int it = 0; it < 2; ++it)                                      \
                aph[p][it] = *(const f16x8*)(Ah + (size_t)rowA16[it] * K + ((kt) << 5) + kcA16); \
        }                                                                       \
    }

#define G_ISSUE_B(kt, p)                                                        \
    {                                                                           \
        _Pragma("unroll")                                                       \
        for (int rd = 0; rd < 2; ++rd)                                          \
            bpre[p][rd] = *(const f16x8*)((const _Float16*)BT +                 \
                (size_t)(n0 + rd * 64 + nB) * K + ((kt) << 5) + kcB);           \
    }

#define G_STAGE(p)                                                              \
    {                                                                           \
        if constexpr (AF32) {                                                   \
            _Pragma("unroll")                                                   \
            for (int it = 0; it < 4; ++it) {                                    \
                int m = it * 32 + (t >> 3);                                     \
                f16x4 hv;                                                       \
                hv.x = (_Float16)apre[p][it][0].x;                              \
                hv.y = (_Float16)apre[p][it][0].y;                              \
                hv.z = (_Float16)apre[p][it][0].z;                              \
                hv.w = (_Float16)apre[p][it][0].w;                              \
                *(f16x4*)(&As[p][0] + m * LS + kcA32) = hv;                     \
            }                                                                   \
        } else {                                                                \
            _Pragma("unroll")                                                   \
            for (int it = 0; it < 2; ++it) {                                    \
                int m = it * 64 + (t >> 2);                                     \
                *(f16x8*)(&As[p][0] + m * LS + kcA16) = aph[p][it];             \
            }                                                                   \
        }                                                                       \
        _Pragma("unroll")                                                       \
        for (int rd = 0; rd < 2; ++rd) {                                        \
            int n = rd * 64 + (t >> 2);                                         \
            *(f16x8*)(&Bs[p][0] + n * LS + kcB) = bpre[p][rd];                  \
        }                                                                       \
    }

#define G_BODY(kk, p)                                                           \
    {                                                                           \
        G_STAGE(p);                                                             \
        asm volatile("s_waitcnt lgkmcnt(0)" ::: "memory");                      \
        __builtin_amdgcn_s_barrier();                                           \
        __builtin_amdgcn_sched_barrier(0);                                      \
        if ((kk) + 2 < T) { G_ISSUE_A((kk) + 2, p); G_ISSUE_B((kk) + 2, p); }   \
        __builtin_amdgcn_sched_barrier(0);                                      \
        f16x8 af[4], bf[4];                                                     \
        _Pragma("unroll")                                                       \
        for (int i = 0; i < 4; ++i)                                             \
            af[i] = *(const f16x8*)(&As[p][0] + (wm + i * 16 + r) * LS + q * 8); \
        _Pragma("unroll")                                                       \
        for (int j = 0; j < 4; ++j)                                             \
            bf[j] = *(const f16x8*)(&Bs[p][0] + (wn + j * 16 + r) * LS + q * 8); \
        _Pragma("unroll")                                                       \
        for (int i = 0; i < 4; ++i)                                             \
            _Pragma("unroll")                                                   \
            for (int j = 0; j < 4; ++j)                                         \
                acc[i][j] = __builtin_amdgcn_mfma_f32_16x16x32_f16(af[i], bf[j], acc[i][j], 0, 0, 0); \
        __builtin_amdgcn_sched_barrier(0);                                      \
    }

    G_ISSUE_A(0, 0); G_ISSUE_B(0, 0);
    G_ISSUE_A(1, 1); G_ISSUE_B(1, 1);

    for (int k = 0; k < T; k += 2) {
        G_BODY(k, 0);
        G_BODY(k + 1, 1);
    }

#pragma unroll
    for (int i = 0; i < 4; ++i) {
#pragma unroll
        for (int reg = 0; reg < 4; ++reg) {
            int m = m0 + wm + i * 16 + q * 4 + reg;
            if (m < M) {
                _Float16* cp = C + (size_t)m * 256 + (n0 + wn + r);
#pragma unroll
                for (int j = 0; j < 4; ++j) cp[j * 16] = (_Float16)acc[i][j][reg];
            }
        }
    }
#undef G_ISSUE_A
#undef G_ISSUE_B
#undef G_STAGE
#undef G_BODY
}

// ---------------- aggregation: out = relu(A_hat @ h + b), f16 in/out ---------
// 1 wave/node. Lane layout: half = lane>>5, l = lane&31; lane covers 8 cols
// [8l, 8l+8). One f16x8 gather instruction fetches TWO edge rows (lower half
// edge j, upper half edge j+1). 16 edges per unrolled batch; slots past the
// edge count have w=0 and src=0 (row-0 broadcast, L1-hot). Split accumulators
// combined with one shfl_xor(32); lanes 0-31 store.
__global__ __launch_bounds__(256) void agg_relu(
    const _Float16* __restrict__ h, const int* __restrict__ roff,
    const int2* __restrict__ edata, const float* __restrict__ dinv,
    const float* __restrict__ bias, _Float16* __restrict__ out, int n)
{
    const int lane = threadIdx.x & 63, wid = threadIdx.x >> 6;
    const int i = blockIdx.x * 4 + wid;
    if (i >= n) return;
    const int half = lane >> 5;
    const int c = (lane & 31) << 3;            // 8 cols per lane
    const float di = dinv[i];
    const float sw = di * di;
    const f16x8 hv = *(const f16x8*)(h + (size_t)i * 256 + c);

    float acc[8];
#pragma unroll
    for (int k = 0; k < 8; ++k) acc[k] = 0.f;

    const int p0 = roff[i], pe = roff[i + 1];
    for (int base = p0; base < pe; base += 64) {
        int lim = pe - base; if (lim > 64) lim = 64;
        int sv = 0; float wv = 0.f;
        if (lane < lim) {
            int2 m = edata[base + lane];
            sv = m.x; wv = __int_as_float(m.y);
        }
        for (int j = 0; j < lim; j += 16) {
            f16x8 vv[8]; float ww[8];
#pragma unroll
            for (int s = 0; s < 8; ++s) {
                int idx = j + 2 * s + half;     // lower half: even slot, upper: odd
                int si = __shfl(sv, idx);
                ww[s] = __shfl(wv, idx);
                vv[s] = *(const f16x8*)(h + (size_t)si * 256 + c);
            }
#pragma unroll
            for (int s = 0; s < 8; ++s)
#pragma unroll
                for (int k = 0; k < 8; ++k)
                    acc[k] += ww[s] * (float)vv[s][k];
        }
    }

    // combine halves (edge j sums in lanes 0-31, edge j+1 sums in lanes 32-63)
    float tot[8];
#pragma unroll
    for (int k = 0; k < 8; ++k) tot[k] = acc[k] + __shfl_xor(acc[k], 32);

    if (half == 0) {
        const float4 bb0 = *(const float4*)(bias + c);
        const float4 bb1 = *(const float4*)(bias + c + 4);
        f16x8 o;
        o[0] = (_Float16)fmaxf(tot[0] + sw * (float)hv[0] + bb0.x, 0.f);
        o[1] = (_Float16)fmaxf(tot[1] + sw * (float)hv[1] + bb0.y, 0.f);
        o[2] = (_Float16)fmaxf(tot[2] + sw * (float)hv[2] + bb0.z, 0.f);
        o[3] = (_Float16)fmaxf(tot[3] + sw * (float)hv[3] + bb0.w, 0.f);
        o[4] = (_Float16)fmaxf(tot[4] + sw * (float)hv[4] + bb1.x, 0.f);
        o[5] = (_Float16)fmaxf(tot[5] + sw * (float)hv[5] + bb1.y, 0.f);
        o[6] = (_Float16)fmaxf(tot[6] + sw * (float)hv[6] + bb1.z, 0.f);
        o[7] = (_Float16)fmaxf(tot[7] + sw * (float)hv[7] + bb1.w, 0.f);
        *(f16x8*)(out + (size_t)i * 256 + c) = o;
    }
}

// ---------------- BatchNorm stats (per-column over rows), f16 in -------------
__global__ __launch_bounds__(256) void bn_stats(const _Float16* __restrict__ h,
    float* __restrict__ bnsum, float* __restrict__ bnsq, int n)
{
    const int t = threadIdx.x, lane = t & 63, g = t >> 6;
    const int c = lane << 2;
    float s0 = 0.f, s1 = 0.f, s2 = 0.f, s3 = 0.f;
    float q0 = 0.f, q1 = 0.f, q2 = 0.f, q3 = 0.f;
    for (int r = blockIdx.x * 4 + g; r < n; r += gridDim.x * 4) {
        f16x4 v = *(const f16x4*)(h + (size_t)r * 256 + c);
        float f0 = (float)v.x, f1 = (float)v.y, f2 = (float)v.z, f3 = (float)v.w;
        s0 += f0; s1 += f1; s2 += f2; s3 += f3;
        q0 += f0 * f0; q1 += f1 * f1; q2 += f2 * f2; q3 += f3 * f3;
    }
    __shared__ float sm[4][256];
    *(float4*)&sm[g][c] = (float4){s0, s1, s2, s3};
    __syncthreads();
    if (g == 0) {
        float4 a = *(float4*)&sm[0][c], b = *(float4*)&sm[1][c];
        float4 d = *(float4*)&sm[2][c], e = *(float4*)&sm[3][c];
        atomicAdd(&bnsum[c + 0], a.x + b.x + d.x + e.x);
        atomicAdd(&bnsum[c + 1], a.y + b.y + d.y + e.y);
        atomicAdd(&bnsum[c + 2], a.z + b.z + d.z + e.z);
        atomicAdd(&bnsum[c + 3], a.w + b.w + d.w + e.w);
    }
    __syncthreads();
    *(float4*)&sm[g][c] = (float4){q0, q1, q2, q3};
    __syncthreads();
    if (g == 0) {
        float4 a = *(float4*)&sm[0][c], b = *(float4*)&sm[1][c];
        float4 d = *(float4*)&sm[2][c], e = *(float4*)&sm[3][c];
        atomicAdd(&bnsq[c + 0], a.x + b.x + d.x + e.x);
        atomicAdd(&bnsq[c + 1], a.y + b.y + d.y + e.y);
        atomicAdd(&bnsq[c + 2], a.z + b.z + d.z + e.z);
        atomicAdd(&bnsq[c + 3], a.w + b.w + d.w + e.w);
    }
}

__global__ __launch_bounds__(256) void bn_params(const float* __restrict__ bnsum,
    const float* __restrict__ bnsq, const float* __restrict__ gamma,
    const float* __restrict__ beta, float* __restrict__ scale,
    float* __restrict__ shift, int n)
{
    int t = threadIdx.x;
    float mu = bnsum[t] / (float)n;
    float var = bnsq[t] / (float)n - mu * mu;
    float sc = gamma[t] * rsqrtf(var + 1e-5f);
    scale[t] = sc;
    shift[t] = beta[t] - mu * sc;
}

// ---------------- fused BN affine + LayerNorm, f16 in / fp32 out -------------
__global__ __launch_bounds__(256) void bn_ln(const _Float16* __restrict__ h,
    const float* __restrict__ scale, const float* __restrict__ shift,
    const float* __restrict__ lng, const float* __restrict__ lnb,
    float* __restrict__ out, int n)
{
    const int lane = threadIdx.x & 63, wid = threadIdx.x >> 6;
    const int i = blockIdx.x * 4 + wid;
    if (i >= n) return;
    const int c = lane << 2;
    const f16x4 v = *(const f16x4*)(h + (size_t)i * 256 + c);
    const float4 sc = *(const float4*)(scale + c);
    const float4 sh = *(const float4*)(shift + c);
    float y0 = (float)v.x * sc.x + sh.x;
    float y1 = (float)v.y * sc.y + sh.y;
    float y2 = (float)v.z * sc.z + sh.z;
    float y3 = (float)v.w * sc.w + sh.w;
    float ps = y0 + y1 + y2 + y3;
    float ps2 = y0 * y0 + y1 * y1 + y2 * y2 + y3 * y3;
#pragma unroll
    for (int off = 32; off > 0; off >>= 1) {
        ps += __shfl_down(ps, off);
        ps2 += __shfl_down(ps2, off);
    }
    ps = __shfl(ps, 0);
    ps2 = __shfl(ps2, 0);
    const float mu = ps * (1.f / 256.f);
    const float var = ps2 * (1.f / 256.f) - mu * mu;
    const float rs = rsqrtf(var + 1e-5f);
    const float4 g = *(const float4*)(lng + c);
    const float4 bb = *(const float4*)(lnb + c);
    float4 o;
    o.x = (y0 - mu) * rs * g.x + bb.x;
    o.y = (y1 - mu) * rs * g.y + bb.y;
    o.z = (y2 - mu) * rs * g.z + bb.z;
    o.w = (y3 - mu) * rs * g.w + bb.w;
    *(float4*)(out + (size_t)i * 256 + c) = o;
}

// ---------------- launcher ---------------------------------------------------
extern "C" void kernel_launch(void* const* d_in, const int* in_sizes, int n_in,
                              void* d_out, int out_size, void* d_ws, size_t ws_size,
                              hipStream_t stream)
{
    const float* x   = (const float*)d_in[0];
    const int*   ei  = (const int*)d_in[1];
    const float* ew  = (const float*)d_in[2];
    const float* W1  = (const float*)d_in[3];
    const float* b1  = (const float*)d_in[4];
    const float* W2  = (const float*)d_in[5];
    const float* b2  = (const float*)d_in[6];
    const float* bng = (const float*)d_in[7];
    const float* bnb = (const float*)d_in[8];
    const float* lng = (const float*)d_in[9];
    const float* lnb = (const float*)d_in[10];
    float* out = (float*)d_out;

    const int N = NN;
    const int E = in_sizes[2];

    char* ws = (char*)d_ws;
    size_t o = 0;
    auto alloc = [&](size_t b) -> char* {
        char* p = ws + o;
        o = (o + b + 255) & ~(size_t)255;
        return p;
    };
    _Float16* h1  = (_Float16*)alloc((size_t)N * NH * 2);   // GEMM out (reused for h2)
    _Float16* h1a = (_Float16*)alloc((size_t)N * NH * 2);
    _Float16* h2a = (_Float16*)alloc((size_t)N * NH * 2);
    unsigned short* W1T = (unsigned short*)alloc((size_t)NH * NF * 2);
    unsigned short* W2T = (unsigned short*)alloc((size_t)NH * NH * 2);
    int2*  edata = (int2*)alloc((size_t)E * 8);
    int*   offs = (int*)alloc((size_t)(N + 1) * 4);
    int*   excl = (int*)alloc((size_t)N * 4);
    int*   bsum = (int*)alloc(512);
    float* dinv = (float*)alloc((size_t)N * 4);
    float* bnscale = (float*)alloc(NH * 4);
    float* bnshift = (float*)alloc(NH * 4);
    char* zbase = ws + o;
    unsigned long long* dc = (unsigned long long*)alloc((size_t)N * 8);
    int*   cursor = (int*)alloc((size_t)N * 4);
    float* bnsum  = (float*)alloc(NH * 4);
    float* bnsq   = (float*)alloc(NH * 4);
    size_t zbytes = (size_t)((ws + o) - zbase);
    (void)hipMemsetAsync(zbase, 0, zbytes, stream);

    cvt_w<<<dim3(NF >> 6, 4), 256, 0, stream>>>(W1, W1T, NF);
    cvt_w<<<dim3(NH >> 6, 4), 256, 0, stream>>>(W2, W2T, NH);
    deg_count<<<(E + 255) / 256, 256, 0, stream>>>(ei, ew, dc, E);
    dinv_k<<<(N + 255) / 256, 256, 0, stream>>>(dc, dinv, N);
    scan_a<<<(N + 511) / 512, 512, 0, stream>>>(dc, excl, bsum, N);
    scan_b<<<1, 128, 0, stream>>>(bsum, (N + 511) / 512);
    scan_c<<<(N + 1 + 255) / 256, 256, 0, stream>>>(excl, bsum, offs, N, E);
    scatter_k<<<(E + 255) / 256, 256, 0, stream>>>(ei, ew, offs, cursor, dinv, edata, E);

    dim3 gg(2, (N + 127) / 128);
    gemm_pipe<true><<<gg, 256, 0, stream>>>(x, W1T, h1, N, NF);
    agg_relu<<<(N + 3) / 4, 256, 0, stream>>>(h1, offs, edata, dinv, b1, h1a, N);
    gemm_pipe<false><<<gg, 256, 0, stream>>>(h1a, W2T, h1, N, NH);
    agg_relu<<<(N + 3) / 4, 256, 0, stream>>>(h1, offs, edata, dinv, b2, h2a, N);

    bn_stats<<<256, 256, 0, stream>>>(h2a, bnsum, bnsq, N);
    bn_params<<<1, 256, 0, stream>>>(bnsum, bnsq, bng, bnb, bnscale, bnshift, N);
    bn_ln<<<(N + 3) / 4, 256, 0, stream>>>(h2a, bnscale, bnshift, lng, lnb, out, N);
}